// Round 10
// baseline (421.274 us; speedup 1.0000x reference)
//
#include <hip/hip_runtime.h>
#include <math.h>

// Problem constants
#define B_    8
#define L_    512
#define K_    16
#define E_    32
#define NH_   64
#define WOFF_ 1

// Workspace layout:
//   flags [256 ints]   @ float-offset 0       (reuses dead qmat region)
//   gi    [B][L][192]  @ float-offset 524288  (786432 floats)

typedef float v2f __attribute__((ext_vector_type(2)));
typedef float v4f __attribute__((ext_vector_type(4)));

// ---------------------------------------------------------------------------
// SINGLE-LAUNCH streaming pipeline.
//
// r9 post-mortem: removing a kernel boundary saved ~0 us => launch overhead
// is NOT the residue; residue is (fused-kernel time + per-iteration fixed
// cost), unattributable from top-5 alone. Either way the fix is the same:
// OVERLAP producer and consumer. k_gru consumes gi strictly in t-order at
// ~0.34 us/step, so with per-chunk ready flags it can run concurrently
// with the producers instead of after them.
//
// Blocks 0..7   : GRU consumer (wave 0 only) — r8-verified inner loop,
//                 re-chunked: before group c (steps 16c..16c+15) it waits
//                 flags[b][c+1] (2-deep ring touches row t+3 max).
// Blocks 8..263 : producers — r9 k_fused body verbatim; block id 8+c*8+b
//                 computes chunk c of batch b (chunk-major => low chunks
//                 finish first); publishes via __syncthreads (drains all
//                 waves' gi stores) + release-agent atomic flag store.
// No deadlock: producers wait on nothing; GRU blocks occupy 8 CUs (93 KB
// LDS => 1 block/CU), 248 CUs run the 256 producers; the 8 queued
// producers (chunk 31) finish ~40 us in, needed at ~163 us.
// All FP op sequences bit-identical to r8/r9.
// ---------------------------------------------------------------------------

#define GRU_STEP(u, DO_REFILL) {                                           \
    v4f hv[16];                                                            \
    _Pragma("unroll")                                                      \
    for (int k = 0; k < 6; ++k) hv[k] = hs4[k];                            \
    const float gr = pr[u], gz = pz[u], gn = pn[u];                        \
    if (DO_REFILL) {                                                       \
        pr[u] = pf[0];                                                     \
        pz[u] = pf[64];                                                    \
        pn[u] = pf[128];                                                   \
        pf += 192;                                                         \
    }                                                                      \
    v2f ar2 = {gr + br, 0.0f};                                             \
    v2f az2 = {gz + bz, 0.0f};                                             \
    v2f an2 = {bn, 0.0f};                                                  \
    _Pragma("unroll")                                                      \
    for (int k = 0; k < 16; ++k) {                                         \
        if (k < 10) hv[k + 6] = hs4[k + 6];                                \
        v2f p0 = __builtin_shufflevector(hv[k], hv[k], 0, 1);              \
        v2f p1 = __builtin_shufflevector(hv[k], hv[k], 2, 3);              \
        ar2 = wr[2*k]     * p0 + ar2;                                      \
        az2 = wz[2*k]     * p0 + az2;                                      \
        an2 = wn[2*k]     * p0 + an2;                                      \
        ar2 = wr[2*k + 1] * p1 + ar2;                                      \
        az2 = wz[2*k + 1] * p1 + az2;                                      \
        an2 = wn[2*k + 1] * p1 + an2;                                      \
    }                                                                      \
    const float ar = ar2.x + ar2.y;                                        \
    const float az = az2.x + az2.y;                                        \
    const float hn = an2.x + an2.y;                                        \
    const float r = __builtin_amdgcn_rcpf(1.0f + __expf(-ar));             \
    const float z = __builtin_amdgcn_rcpf(1.0f + __expf(-az));             \
    float npre = gn + r * hn;                                              \
    npre = fminf(fmaxf(npre, -15.0f), 15.0f);                              \
    const float e2 = __expf(2.0f * npre);                                  \
    const float n  = (e2 - 1.0f) * __builtin_amdgcn_rcpf(e2 + 1.0f);       \
    h = fmaf(z, h - n, n);                                                 \
    hsg[lane] = h;                                                         \
    *outp = h;                                                             \
    outp += 64;                                                            \
}

#define WAITFLAG(bb, cc)                                                   \
    while (__hip_atomic_load(&flags[((bb) << 5) + (cc)],                   \
           __ATOMIC_ACQUIRE, __HIP_MEMORY_SCOPE_AGENT) == 0)               \
        __builtin_amdgcn_s_sleep(8);

__global__ __launch_bounds__(256, 1) void k_mega(
    const float* __restrict__ ts,   const float* __restrict__ val,
    const int*   __restrict__ mark, const float* __restrict__ npm,
    const float* __restrict__ Wl,   const float* __restrict__ bl,
    const float* __restrict__ Wp,   const float* __restrict__ bp,
    const float* __restrict__ Wq,   const float* __restrict__ bq,
    const float* __restrict__ Wk,   const float* __restrict__ bk,
    const float* __restrict__ Wo,   const float* __restrict__ bo,
    const float* __restrict__ Wih,  const float* __restrict__ bih,
    const float* __restrict__ Whh,  const float* __restrict__ bhh,
    float* __restrict__ gi,         int* __restrict__ flags,
    float* __restrict__ out)
{
    // ---- LDS (union of both paths' needs; ~93 KB => 1 block/CU) ----
    __shared__ float kL[32 * 512];    // K^T for batch b (64 KB)
    __shared__ float qL[16 * 32];
    __shared__ float srow[4 * 512];
    __shared__ int   cc[512];
    __shared__ float vv[512];
    __shared__ float attL[16 * 64];
    __shared__ float WqL[1024], WkL[1024];
    __shared__ float bqL[32], bkL[32], WpL[31], bpL[31];
    __shared__ float wl0, bl0;
    __shared__ float hsg[64];         // GRU h-broadcast buffer

    const int tid = threadIdx.x;

    // =======================================================================
    // CONSUMER PATH: blocks 0..7 — GRU for batch b, wave 0 only.
    // =======================================================================
    if (blockIdx.x < 8) {
        if (tid >= 64) return;        // waves 1..3 exit; no barriers below
        const int lane = tid;         // 0..63
        const int b    = blockIdx.x;  // 0..7

        // Stage this lane's three W_hh rows into registers.
        v2f wr[32], wz[32], wn[32];
        {
            const v2f* r2 = (const v2f*)(Whh + (size_t)lane * 64);
            const v2f* z2 = (const v2f*)(Whh + (size_t)(lane + 64) * 64);
            const v2f* n2 = (const v2f*)(Whh + (size_t)(lane + 128) * 64);
            #pragma unroll
            for (int j = 0; j < 32; ++j) {
                wr[j] = r2[j];
                wz[j] = z2[j];
                wn[j] = n2[j];
            }
        }
        const float br = bhh[lane];
        const float bz = bhh[lane + 64];
        const float bn = bhh[lane + 128];

        const float* gib  = gi  + (size_t)b * 512 * 192;
        float*       outp = out + (size_t)b * 512 * 64 + lane;

        float h = 0.0f;
        hsg[lane] = 0.0f;             // h_{-1} = 0 (same wave; DS in-order)

        // chunk 0 must be ready before ring init (rows 0,1)
        WAITFLAG(b, 0)

        float pr[2], pz[2], pn[2];
        #pragma unroll
        for (int i = 0; i < 2; ++i) {
            const float* gp = gib + (size_t)i * 192;
            pr[i] = gp[lane];
            pz[i] = gp[lane + 64];
            pn[i] = gp[lane + 128];
        }
        const float* pf = gib + (size_t)2 * 192 + lane;

        const v4f* hs4 = (const v4f*)hsg;

        // 32 chunk-groups of 16 steps; group c's refills touch chunk c+1
        for (int c = 0; c < 32; ++c) {
            if (c < 31) {
                WAITFLAG(b, c + 1)
                for (int g8 = 0; g8 < 8; ++g8) {
                    GRU_STEP(0, 1)
                    GRU_STEP(1, 1)
                }
            } else {
                for (int g8 = 0; g8 < 7; ++g8) {
                    GRU_STEP(0, 1)
                    GRU_STEP(1, 1)
                }
                GRU_STEP(0, 0)        // steps 510, 511: no refill
                GRU_STEP(1, 0)
            }
        }
        return;
    }

    // =======================================================================
    // PRODUCER PATH: blocks 8..263 — chunk qb of batch b (r9 body verbatim).
    // =======================================================================
    const int pid = blockIdx.x - 8;
    const int qb  = pid >> 3;         // 0..31  (chunk-major: low chunks first)
    const int b   = pid & 7;          // 0..7
    const int qb0 = qb * 16;

    // ---- stage small weights + masks ----
    {
        float4 v = ((const float4*)Wq)[tid];
        ((float4*)WqL)[tid] = v;
        float4 u = ((const float4*)Wk)[tid];
        ((float4*)WkL)[tid] = u;
    }
    if (tid < 32) { bqL[tid] = bq[tid]; bkL[tid] = bk[tid]; }
    if (tid < 31) { WpL[tid] = Wp[tid]; bpL[tid] = bp[tid]; }
    if (tid == 0) { wl0 = Wl[0]; bl0 = bl[0]; }
    for (int k = tid; k < 512; k += 256) {
        const int   m  = mark[b * 512 + k];
        const float np = npm[b * 512 + k];
        cc[k] = (np > 0.0f) ? (m - 1) : -1;
        vv[k] = val[b * 512 + k];
    }
    __syncthreads();

    // ---- embed recompute (bit-identical to k_embed op order) ----
    for (int l = tid; l < 512; l += 256) {
        const float t = ts[b * 512 + l];
        float e[32];
        e[0] = t * wl0 + bl0;
        #pragma unroll
        for (int j = 1; j < 32; ++j) e[j] = sinf(t * WpL[j - 1] + bpL[j - 1]);

        const bool ownq = (l >= qb0) && (l < qb0 + 16);
        float* qrow = qL + (l - qb0) * 32;

        for (int dq = 0; dq < 8; ++dq) {
            float k0 = bkL[4*dq+0], k1 = bkL[4*dq+1], k2 = bkL[4*dq+2], k3 = bkL[4*dq+3];
            const float* wk = &WkL[(4*dq) * 32];
            #pragma unroll
            for (int j = 0; j < 32; ++j) {
                const float ej = e[j];
                k0 = fmaf(wk[j],      ej, k0);
                k1 = fmaf(wk[32 + j], ej, k1);
                k2 = fmaf(wk[64 + j], ej, k2);
                k3 = fmaf(wk[96 + j], ej, k3);
            }
            kL[(4*dq + 0) * 512 + l] = k0;
            kL[(4*dq + 1) * 512 + l] = k1;
            kL[(4*dq + 2) * 512 + l] = k2;
            kL[(4*dq + 3) * 512 + l] = k3;

            if (ownq) {
                float q0 = bqL[4*dq+0], q1 = bqL[4*dq+1], q2 = bqL[4*dq+2], q3 = bqL[4*dq+3];
                const float* wq = &WqL[(4*dq) * 32];
                #pragma unroll
                for (int j = 0; j < 32; ++j) {
                    const float ej = e[j];
                    q0 = fmaf(wq[j],      ej, q0);
                    q1 = fmaf(wq[32 + j], ej, q1);
                    q2 = fmaf(wq[64 + j], ej, q2);
                    q3 = fmaf(wq[96 + j], ej, q3);
                }
                qrow[4*dq + 0] = q0;
                qrow[4*dq + 1] = q1;
                qrow[4*dq + 2] = q2;
                qrow[4*dq + 3] = q3;
            }
        }
    }
    __syncthreads();

    // ---- attention ----
    const int w = tid >> 6, lane = tid & 63;

    for (int iq = 0; iq < 4; ++iq) {
        const int q = qb0 + w * 4 + iq;

        float qr[32];
        const float4* qm4 = (const float4*)(qL + (size_t)(q - qb0) * 32);
        #pragma unroll
        for (int j4 = 0; j4 < 8; ++j4) {
            float4 v = qm4[j4];
            qr[4*j4+0] = v.x; qr[4*j4+1] = v.y; qr[4*j4+2] = v.z; qr[4*j4+3] = v.w;
        }

        float acc[8];
        #pragma unroll
        for (int m = 0; m < 8; ++m) acc[m] = 0.0f;
        #pragma unroll 4
        for (int j = 0; j < 32; ++j) {
            const float* row = kL + j * 512 + lane;
            const float  qj  = qr[j];
            #pragma unroll
            for (int m = 0; m < 8; ++m) acc[m] = fmaf(qj, row[m * 64], acc[m]);
        }
        #pragma unroll
        for (int m = 0; m < 8; ++m)
            srow[w * 512 + m * 64 + lane] = acc[m] * 0.17677669529663687f;
        __syncthreads();

        const int c = lane & 15, s = lane >> 4;
        float mx = -1e30f, Z = 0.0f, X = 0.0f;
        const int base = s * 128;
        for (int t = 0; t < 128; ++t) {
            const int k = base + ((t + s) & 127);
            if (cc[k] == c) {
                const float l  = (k <= q + WOFF_) ? srow[w * 512 + k] : 0.0f;
                const float mn = fmaxf(mx, l);
                const float e1 = __expf(l - mn);
                const float sc = __expf(mx - mn);
                Z = Z * sc + e1;
                X = X * sc + e1 * vv[k];
                mx = mn;
            }
        }
        #pragma unroll
        for (int off = 16; off <= 32; off <<= 1) {
            const float mo = __shfl_xor(mx, off);
            const float Zo = __shfl_xor(Z, off);
            const float Xo = __shfl_xor(X, off);
            const float mn = fmaxf(mx, mo);
            const float a0 = __expf(mx - mn);
            const float a1 = __expf(mo - mn);
            Z = Z * a0 + Zo * a1;
            X = X * a0 + Xo * a1;
            mx = mn;
        }
        const float x = (Z > 0.0f) ? X / Z : 0.0f;

        float xs[16];
        #pragma unroll
        for (int c2 = 0; c2 < 16; ++c2) xs[c2] = __shfl(x, c2);

        const float4* wo4 = (const float4*)(Wo + lane * 16);
        float a = bo[lane];
        #pragma unroll
        for (int c4 = 0; c4 < 4; ++c4) {
            float4 v = wo4[c4];
            a += xs[4*c4+0] * v.x + xs[4*c4+1] * v.y + xs[4*c4+2] * v.z + xs[4*c4+3] * v.w;
        }
        attL[(w * 4 + iq) * 64 + lane] = a;
        __syncthreads();
    }

    // ---- gi tail (Wih/bih from global; bit-exact) ----
    const size_t out0 = (size_t)(b * 32 + qb) * 16 * 192;
    for (int pp = 0; pp < 12; ++pp) {
        const int p = tid + 256 * pp;
        const int r = p / 192, g = p - r * 192;
        float a0 = bih[g], a1 = 0.f, a2 = 0.f, a3 = 0.f;
        const float* wrow = Wih + g * 64;
        const float* arow = &attL[r * 64];
        #pragma unroll
        for (int j = 0; j < 64; j += 4) {
            a0 = fmaf(arow[j + 0], wrow[j + 0], a0);
            a1 = fmaf(arow[j + 1], wrow[j + 1], a1);
            a2 = fmaf(arow[j + 2], wrow[j + 2], a2);
            a3 = fmaf(arow[j + 3], wrow[j + 3], a3);
        }
        gi[out0 + p] = (a0 + a1) + (a2 + a3);
    }

    // ---- publish: drain all waves' gi stores, then release flag ----
    __syncthreads();                  // compiler emits vmcnt(0) before barrier
    if (tid == 0) {
        __threadfence();
        __hip_atomic_store(&flags[(b << 5) + qb], 1,
                           __ATOMIC_RELEASE, __HIP_MEMORY_SCOPE_AGENT);
    }
}

// ---------------------------------------------------------------------------
extern "C" void kernel_launch(void* const* d_in, const int* in_sizes, int n_in,
                              void* d_out, int out_size, void* d_ws, size_t ws_size,
                              hipStream_t stream)
{
    const float* ts   = (const float*)d_in[0];
    const float* val  = (const float*)d_in[1];
    const int*   mark = (const int*)  d_in[2];
    const float* npm  = (const float*)d_in[3];
    const float* Wl   = (const float*)d_in[4];
    const float* bl   = (const float*)d_in[5];
    const float* Wp   = (const float*)d_in[6];
    const float* bp   = (const float*)d_in[7];
    const float* Wq   = (const float*)d_in[8];
    const float* bq   = (const float*)d_in[9];
    const float* Wk   = (const float*)d_in[10];
    const float* bk   = (const float*)d_in[11];
    const float* Wo   = (const float*)d_in[12];
    const float* bo   = (const float*)d_in[13];
    const float* Wih  = (const float*)d_in[14];
    const float* Whh  = (const float*)d_in[15];
    const float* bih  = (const float*)d_in[16];
    const float* bhh  = (const float*)d_in[17];

    float* ws    = (float*)d_ws;
    int*   flags = (int*)d_ws;         // 256 ints @ offset 0 (dead qmat region)
    float* gi    = ws + 524288;        // 786432 floats
    float* out   = (float*)d_out;

    hipMemsetAsync(flags, 0, 256 * sizeof(int), stream);
    k_mega<<<264, 256, 0, stream>>>(ts, val, mark, npm, Wl, bl, Wp, bp,
                                    Wq, bq, Wk, bk, Wo, bo, Wih, bih,
                                    Whh, bhh, gi, flags, out);
}

// Round 12
// 326.941 us; speedup vs baseline: 1.2885x; 1.2885x over previous
//
#include <hip/hip_runtime.h>
#include <math.h>

// Problem constants
#define B_    8
#define L_    512
#define K_    16
#define E_    32
#define NH_   64
#define WOFF_ 1

// Workspace layout (floats):
//   qmat  [B][L][32]   @ 0        (131072)
//   kmatT [B][32][L]   @ 131072   (131072)
//   gi    [B][L][192]  @ 524288   (786432)

typedef float v2f __attribute__((ext_vector_type(2)));
typedef float v4f __attribute__((ext_vector_type(4)));

// ---------------------------------------------------------------------------
// Kernel 1: key_emb -> q, k projections. One thread per (b,l). (r8 form)
// ---------------------------------------------------------------------------
__global__ __launch_bounds__(256) void k_embed(
    const float* __restrict__ ts, const float* __restrict__ Wl,
    const float* __restrict__ bl, const float* __restrict__ Wp,
    const float* __restrict__ bp, const float* __restrict__ Wq,
    const float* __restrict__ bq, const float* __restrict__ Wk,
    const float* __restrict__ bk,
    float* __restrict__ qmat, float* __restrict__ kmatT)
{
    __shared__ float WqL[1024], WkL[1024];
    __shared__ float bqL[32], bkL[32], WpL[31], bpL[31];
    __shared__ float wl0, bl0;
    const int tid = threadIdx.x;

    {
        float4 v = ((const float4*)Wq)[tid];
        ((float4*)WqL)[tid] = v;
        float4 u = ((const float4*)Wk)[tid];
        ((float4*)WkL)[tid] = u;
    }
    if (tid < 32) { bqL[tid] = bq[tid]; bkL[tid] = bk[tid]; }
    if (tid < 31) { WpL[tid] = Wp[tid]; bpL[tid] = bp[tid]; }
    if (tid == 0) { wl0 = Wl[0]; bl0 = bl[0]; }
    __syncthreads();

    const int p = blockIdx.x * 256 + tid;      // 0..4095
    const float t = ts[p];
    float e[32];
    e[0] = t * wl0 + bl0;
    #pragma unroll
    for (int j = 1; j < 32; ++j) e[j] = sinf(t * WpL[j - 1] + bpL[j - 1]);

    const int b = p >> 9, l = p & 511;
    float4* qm4 = (float4*)(qmat + (size_t)p * 32);
    float*  kT  = kmatT + (size_t)b * 32 * 512 + l;

    for (int dq = 0; dq < 8; ++dq) {
        float q0 = bqL[4*dq+0], q1 = bqL[4*dq+1], q2 = bqL[4*dq+2], q3 = bqL[4*dq+3];
        float k0 = bkL[4*dq+0], k1 = bkL[4*dq+1], k2 = bkL[4*dq+2], k3 = bkL[4*dq+3];
        const float* wq = &WqL[(4*dq) * 32];
        const float* wk = &WkL[(4*dq) * 32];
        #pragma unroll
        for (int j = 0; j < 32; ++j) {
            const float ej = e[j];
            q0 = fmaf(wq[j],      ej, q0);
            q1 = fmaf(wq[32 + j], ej, q1);
            q2 = fmaf(wq[64 + j], ej, q2);
            q3 = fmaf(wq[96 + j], ej, q3);
            k0 = fmaf(wk[j],      ej, k0);
            k1 = fmaf(wk[32 + j], ej, k1);
            k2 = fmaf(wk[64 + j], ej, k2);
            k3 = fmaf(wk[96 + j], ej, k3);
        }
        qm4[dq] = make_float4(q0, q1, q2, q3);
        kT[(4*dq + 0) * 512] = k0;
        kT[(4*dq + 1) * 512] = k1;
        kT[(4*dq + 2) * 512] = k2;
        kT[(4*dq + 3) * 512] = k3;
    }
}

// ---------------------------------------------------------------------------
// Kernel 2 (attn + gi, HIGH OCCUPANCY): grid (128 qb, 8 b), 256 thr.
//
// r10 post-mortem: producer block time ~130 us at 1 wave/SIMD chip-wide
// (256 blocks x 4 waves on 256 CUs, LDS-capped) — latency-exposed, not
// issue-bound. Fix: 1024 blocks x 4 waves = 4 waves/SIMD. Each block does
// 4 q-rows (one per wave, iq loop gone); LDS cut to ~13 KB by reading
// kmatT/qmat/Wo/Wih/bih straight from global (L2-hot; r9 validated global
// Wih/bih as bit-exact). srow slices are wave-private -> per-iq barriers
// dropped (ds in-order within a wave). All FP op sequences verbatim from
// r8/r9 => bit-identical output.
// ---------------------------------------------------------------------------
__global__ __launch_bounds__(256) void k_attn_gi(
    const float* __restrict__ qmat, const float* __restrict__ kmatT,
    const float* __restrict__ val,  const int*   __restrict__ mark,
    const float* __restrict__ npm,  const float* __restrict__ Wo,
    const float* __restrict__ bo,   const float* __restrict__ Wih,
    const float* __restrict__ bih,  float* __restrict__ gi)
{
    __shared__ float srow[4 * 512];   // per-wave score row (8 KB)
    __shared__ int   cc[512];         // category (-1 if padded)
    __shared__ float vv[512];         // values
    __shared__ float attL[4 * 64];    // this block's 4 att rows
    const int tid = threadIdx.x;
    const int qb  = blockIdx.x;       // 0..127
    const int b   = blockIdx.y;       // 0..7
    const int qb0 = qb * 4;

    for (int k = tid; k < 512; k += 256) {
        const int   m  = mark[b * 512 + k];
        const float np = npm[b * 512 + k];
        cc[k] = (np > 0.0f) ? (m - 1) : -1;
        vv[k] = val[b * 512 + k];
    }
    __syncthreads();

    const int w = tid >> 6, lane = tid & 63;
    const float* kTb = kmatT + (size_t)b * 32 * 512;
    const int q = qb0 + w;            // this wave's q row

    {
        float qr[32];
        const float4* qm4 = (const float4*)(qmat + (size_t)(b * 512 + q) * 32);
        #pragma unroll
        for (int j4 = 0; j4 < 8; ++j4) {
            float4 v = qm4[j4];
            qr[4*j4+0] = v.x; qr[4*j4+1] = v.y; qr[4*j4+2] = v.z; qr[4*j4+3] = v.w;
        }

        float acc[8];
        #pragma unroll
        for (int m = 0; m < 8; ++m) acc[m] = 0.0f;
        #pragma unroll 4
        for (int j = 0; j < 32; ++j) {
            const float* row = kTb + j * 512 + lane;
            const float  qj  = qr[j];
            #pragma unroll
            for (int m = 0; m < 8; ++m) acc[m] = fmaf(qj, row[m * 64], acc[m]);
        }
        #pragma unroll
        for (int m = 0; m < 8; ++m)
            srow[w * 512 + m * 64 + lane] = acc[m] * 0.17677669529663687f;
        // srow slice is wave-private; ds in-order => no barrier needed

        const int c = lane & 15, s = lane >> 4;
        float mx = -1e30f, Z = 0.0f, X = 0.0f;
        const int base = s * 128;
        for (int t = 0; t < 128; ++t) {
            const int k = base + ((t + s) & 127);
            if (cc[k] == c) {
                const float l  = (k <= q + WOFF_) ? srow[w * 512 + k] : 0.0f;
                const float mn = fmaxf(mx, l);
                const float e1 = __expf(l - mn);
                const float sc = __expf(mx - mn);
                Z = Z * sc + e1;
                X = X * sc + e1 * vv[k];
                mx = mn;
            }
        }
        #pragma unroll
        for (int off = 16; off <= 32; off <<= 1) {
            const float mo = __shfl_xor(mx, off);
            const float Zo = __shfl_xor(Z, off);
            const float Xo = __shfl_xor(X, off);
            const float mn = fmaxf(mx, mo);
            const float a0 = __expf(mx - mn);
            const float a1 = __expf(mo - mn);
            Z = Z * a0 + Zo * a1;
            X = X * a0 + Xo * a1;
            mx = mn;
        }
        const float x = (Z > 0.0f) ? X / Z : 0.0f;

        float xs[16];
        #pragma unroll
        for (int c2 = 0; c2 < 16; ++c2) xs[c2] = __shfl(x, c2);

        const float4* wo4 = (const float4*)(Wo + lane * 16);
        float a = bo[lane];
        #pragma unroll
        for (int c4 = 0; c4 < 4; ++c4) {
            float4 v = wo4[c4];
            a += xs[4*c4+0] * v.x + xs[4*c4+1] * v.y + xs[4*c4+2] * v.z + xs[4*c4+3] * v.w;
        }
        attL[w * 64 + lane] = a;      // row stays in LDS
    }
    __syncthreads();                  // all 4 attL rows visible

    // ---- gi part: 4 rows x 192 = 768 outputs, 3 passes of 256 ----
    const size_t out0 = (size_t)(b * 512 + qb0) * 192;
    for (int pp = 0; pp < 3; ++pp) {
        const int p = tid + 256 * pp;
        const int r = p / 192, g = p - r * 192;
        float a0 = bih[g], a1 = 0.f, a2 = 0.f, a3 = 0.f;
        const float* wrow = Wih + g * 64;
        const float* arow = &attL[r * 64];
        #pragma unroll
        for (int j = 0; j < 64; j += 4) {
            a0 = fmaf(arow[j + 0], wrow[j + 0], a0);
            a1 = fmaf(arow[j + 1], wrow[j + 1], a1);
            a2 = fmaf(arow[j + 2], wrow[j + 2], a2);
            a3 = fmaf(arow[j + 3], wrow[j + 3], a3);
        }
        gi[out0 + p] = (a0 + a1) + (a2 + a3);
    }
}

// ---------------------------------------------------------------------------
// Kernel 3: sequential GRU — r8-verified form, UNCHANGED (175 us).
// ---------------------------------------------------------------------------

#define GRU_STEP(u, DO_REFILL) {                                           \
    v4f hv[16];                                                            \
    _Pragma("unroll")                                                      \
    for (int k = 0; k < 6; ++k) hv[k] = hs4[k];                            \
    const float gr = pr[u], gz = pz[u], gn = pn[u];                        \
    if (DO_REFILL) {                                                       \
        pr[u] = pf[0];                                                     \
        pz[u] = pf[64];                                                    \
        pn[u] = pf[128];                                                   \
        pf += 192;                                                         \
    }                                                                      \
    v2f ar2 = {gr + br, 0.0f};                                             \
    v2f az2 = {gz + bz, 0.0f};                                             \
    v2f an2 = {bn, 0.0f};                                                  \
    _Pragma("unroll")                                                      \
    for (int k = 0; k < 16; ++k) {                                         \
        if (k < 10) hv[k + 6] = hs4[k + 6];                                \
        v2f p0 = __builtin_shufflevector(hv[k], hv[k], 0, 1);              \
        v2f p1 = __builtin_shufflevector(hv[k], hv[k], 2, 3);              \
        ar2 = wr[2*k]     * p0 + ar2;                                      \
        az2 = wz[2*k]     * p0 + az2;                                      \
        an2 = wn[2*k]     * p0 + an2;                                      \
        ar2 = wr[2*k + 1] * p1 + ar2;                                      \
        az2 = wz[2*k + 1] * p1 + az2;                                      \
        an2 = wn[2*k + 1] * p1 + an2;                                      \
    }                                                                      \
    const float ar = ar2.x + ar2.y;                                        \
    const float az = az2.x + az2.y;                                        \
    const float hn = an2.x + an2.y;                                        \
    const float r = __builtin_amdgcn_rcpf(1.0f + __expf(-ar));             \
    const float z = __builtin_amdgcn_rcpf(1.0f + __expf(-az));             \
    float npre = gn + r * hn;                                              \
    npre = fminf(fmaxf(npre, -15.0f), 15.0f);                              \
    const float e2 = __expf(2.0f * npre);                                  \
    const float n  = (e2 - 1.0f) * __builtin_amdgcn_rcpf(e2 + 1.0f);       \
    h = fmaf(z, h - n, n);                                                 \
    hs[lane] = h;                                                          \
    *outp = h;                                                             \
    outp += 64;                                                            \
}

__global__ __launch_bounds__(64, 1) void k_gru(
    const float* __restrict__ gi, const float* __restrict__ Whh,
    const float* __restrict__ bhh, float* __restrict__ out)
{
    __shared__ float hs[64];
    const int lane = threadIdx.x;     // 0..63
    const int b    = blockIdx.x;      // 0..7

    v2f wr[32], wz[32], wn[32];
    {
        const v2f* r2 = (const v2f*)(Whh + (size_t)lane * 64);
        const v2f* z2 = (const v2f*)(Whh + (size_t)(lane + 64) * 64);
        const v2f* n2 = (const v2f*)(Whh + (size_t)(lane + 128) * 64);
        #pragma unroll
        for (int j = 0; j < 32; ++j) {
            wr[j] = r2[j];
            wz[j] = z2[j];
            wn[j] = n2[j];
        }
    }
    const float br = bhh[lane];
    const float bz = bhh[lane + 64];
    const float bn = bhh[lane + 128];

    const float* gib  = gi  + (size_t)b * 512 * 192;
    float*       outp = out + (size_t)b * 512 * 64 + lane;

    float h = 0.0f;
    hs[lane] = 0.0f;                  // h_{-1} = 0 (same wave; DS in-order)

    float pr[2], pz[2], pn[2];
    #pragma unroll
    for (int i = 0; i < 2; ++i) {
        const float* gp = gib + (size_t)i * 192;
        pr[i] = gp[lane];
        pz[i] = gp[lane + 64];
        pn[i] = gp[lane + 128];
    }
    const float* pf = gib + (size_t)2 * 192 + lane;

    const v4f* hs4 = (const v4f*)hs;

    for (int tt = 0; tt < 510; tt += 2) {
        GRU_STEP(0, 1)
        GRU_STEP(1, 1)
    }
    GRU_STEP(0, 0)
    GRU_STEP(1, 0)
}

// ---------------------------------------------------------------------------
extern "C" void kernel_launch(void* const* d_in, const int* in_sizes, int n_in,
                              void* d_out, int out_size, void* d_ws, size_t ws_size,
                              hipStream_t stream)
{
    const float* ts   = (const float*)d_in[0];
    const float* val  = (const float*)d_in[1];
    const int*   mark = (const int*)  d_in[2];
    const float* npm  = (const float*)d_in[3];
    const float* Wl   = (const float*)d_in[4];
    const float* bl   = (const float*)d_in[5];
    const float* Wp   = (const float*)d_in[6];
    const float* bp   = (const float*)d_in[7];
    const float* Wq   = (const float*)d_in[8];
    const float* bq   = (const float*)d_in[9];
    const float* Wk   = (const float*)d_in[10];
    const float* bk   = (const float*)d_in[11];
    const float* Wo   = (const float*)d_in[12];
    const float* bo   = (const float*)d_in[13];
    const float* Wih  = (const float*)d_in[14];
    const float* Whh  = (const float*)d_in[15];
    const float* bih  = (const float*)d_in[16];
    const float* bhh  = (const float*)d_in[17];

    float* ws    = (float*)d_ws;
    float* qmat  = ws;                 // 131072
    float* kmatT = ws + 131072;        // 131072
    float* gi    = ws + 524288;        // 786432
    float* out   = (float*)d_out;

    k_embed<<<16, 256, 0, stream>>>(ts, Wl, bl, Wp, bp, Wq, bq, Wk, bk, qmat, kmatT);
    k_attn_gi<<<dim3(128, 8), 256, 0, stream>>>(qmat, kmatT, val, mark, npm,
                                                Wo, bo, Wih, bih, gi);
    k_gru<<<8, 64, 0, stream>>>(gi, Whh, bhh, out);
}